// Round 2
// 237.820 us; speedup vs baseline: 1.0413x; 1.0413x over previous
//
#include <hip/hip_runtime.h>

// out[N,32] = segment_sum(edge_val[e] * weight[edge_col[e], :], edge_row[e]) + bias
//
// v2b (retry of v2 after infra failure): bin-by-row + gather.
// Replaces 51.2M float atomicAdds (atomic-op-throughput bound, ~170us floor) with:
//   K0 gnn_init   : out = bias (float4 stores), cnt = 0
//   K1 gnn_bin    : per edge, slot = atomicAdd(cnt[row]) (1.6M int atomics),
//                   store (col,val) as 8B into bins[row*cap+slot].
//                   Overflow (slot>=cap, astronomically rare for Poisson(16) with
//                   cap>=16) falls back to direct atomics into out.
//   K2 gnn_gather : 32 lanes per row, register accumulate over the row's bin
//                   entries, one coalesced read-modify-write of the out row.

#define FEAT 32
#define CAP_MAX 32

__global__ __launch_bounds__(256) void gnn_init(
    const float* __restrict__ bias, float* __restrict__ out,
    int* __restrict__ cnt, int total4, int n_nodes) {
    int i = blockIdx.x * blockDim.x + threadIdx.x;
    if (i < total4) {
        // element index = 4*i; float4 slot within the 32-wide row = i&7
        float4 b = ((const float4*)bias)[i & 7];
        ((float4*)out)[i] = b;
    }
    if (i < n_nodes) cnt[i] = 0;
}

__global__ __launch_bounds__(256) void gnn_bin(
    const int* __restrict__ edge_row,
    const int* __restrict__ edge_col,
    const float* __restrict__ edge_val,
    const float* __restrict__ weight,
    float2* __restrict__ bins,
    int* __restrict__ cnt,
    float* __restrict__ out,
    int num_edges, int cap) {
    int e = blockIdx.x * blockDim.x + threadIdx.x;
    if (e >= num_edges) return;
    int r = edge_row[e];
    int c = edge_col[e];
    float v = edge_val[e];
    int slot = atomicAdd(&cnt[r], 1);
    if (slot < cap) {
        bins[(long long)r * cap + slot] = make_float2(__int_as_float(c), v);
    } else {
        // Rare overflow path: direct atomic accumulate (out holds bias already).
        const float* w = weight + (long long)c * FEAT;
        #pragma unroll
        for (int f = 0; f < FEAT; ++f)
            atomicAdd(out + (long long)r * FEAT + f, v * w[f]);
    }
}

__global__ __launch_bounds__(256) void gnn_gather(
    const float2* __restrict__ bins,
    const int* __restrict__ cnt,
    const float* __restrict__ weight,
    float* __restrict__ out,
    int n_nodes, int cap) {
    int g = (blockIdx.x * blockDim.x + threadIdx.x) >> 5;  // row, 32 lanes each
    int f = threadIdx.x & (FEAT - 1);
    if (g >= n_nodes) return;
    int n = cnt[g];                 // broadcast load (same addr across 32 lanes)
    n = n < cap ? n : cap;
    const float2* b = bins + (long long)g * cap;
    float acc0 = 0.f, acc1 = 0.f, acc2 = 0.f, acc3 = 0.f;
    int j = 0;
    // 4-way unroll: 4 independent weight gathers in flight per group hides the
    // dependent (bin load -> addr -> weight load) latency chain.
    for (; j + 4 <= n; j += 4) {
        float2 e0 = b[j], e1 = b[j + 1], e2 = b[j + 2], e3 = b[j + 3];
        float w0 = weight[(long long)__float_as_int(e0.x) * FEAT + f];
        float w1 = weight[(long long)__float_as_int(e1.x) * FEAT + f];
        float w2 = weight[(long long)__float_as_int(e2.x) * FEAT + f];
        float w3 = weight[(long long)__float_as_int(e3.x) * FEAT + f];
        acc0 += e0.y * w0;
        acc1 += e1.y * w1;
        acc2 += e2.y * w2;
        acc3 += e3.y * w3;
    }
    for (; j < n; ++j) {
        float2 e0 = b[j];
        acc0 += e0.y * weight[(long long)__float_as_int(e0.x) * FEAT + f];
    }
    float acc = (acc0 + acc1) + (acc2 + acc3);
    // out already holds bias (+ rare overflow contributions)
    out[(long long)g * FEAT + f] += acc;
}

// ---- fallback path (original kernels), used only if workspace is too small ----

__global__ __launch_bounds__(256) void gnn_init_out(
    const float* __restrict__ bias, float* __restrict__ out, int total) {
    int i = blockIdx.x * blockDim.x + threadIdx.x;
    if (i < total) out[i] = bias[i & (FEAT - 1)];
}

__global__ __launch_bounds__(256) void gnn_scatter(
    const int* __restrict__ edge_row,
    const int* __restrict__ edge_col,
    const float* __restrict__ edge_val,
    const float* __restrict__ weight,
    float* __restrict__ out,
    int num_edges) {
    long long t = (long long)blockIdx.x * blockDim.x + threadIdx.x;
    int e = (int)(t >> 5);
    int f = (int)(t & (FEAT - 1));
    if (e < num_edges) {
        int r = edge_row[e];
        int c = edge_col[e];
        float v = edge_val[e];
        float w = weight[c * FEAT + f];
        atomicAdd(out + r * FEAT + f, v * w);
    }
}

extern "C" void kernel_launch(void* const* d_in, const int* in_sizes, int n_in,
                              void* d_out, int out_size, void* d_ws, size_t ws_size,
                              hipStream_t stream) {
    const int*   edge_row = (const int*)d_in[0];
    const int*   edge_col = (const int*)d_in[1];
    const float* edge_val = (const float*)d_in[2];
    const float* weight   = (const float*)d_in[3];
    const float* bias     = (const float*)d_in[4];
    float* out = (float*)d_out;

    const int E = in_sizes[0];
    const int total = out_size;        // N * 32 elements
    const int N = total / FEAT;

    // Workspace layout: cnt[N] ints (256B-aligned region), then bins[N*cap] float2
    size_t cnt_bytes = ((size_t)N * sizeof(int) + 255) & ~(size_t)255;
    long long cap_ll = 0;
    if (ws_size > cnt_bytes)
        cap_ll = (long long)((ws_size - cnt_bytes) / ((size_t)N * sizeof(float2)));
    int cap = (int)(cap_ll > CAP_MAX ? CAP_MAX : cap_ll);

    if (cap >= 16) {
        int* cnt = (int*)d_ws;
        float2* bins = (float2*)((char*)d_ws + cnt_bytes);

        int total4 = total / 4;
        int init_threads = total4 > N ? total4 : N;
        gnn_init<<<(init_threads + 255) / 256, 256, 0, stream>>>(
            bias, out, cnt, total4, N);

        gnn_bin<<<(E + 255) / 256, 256, 0, stream>>>(
            edge_row, edge_col, edge_val, weight, bins, cnt, out, E, cap);

        long long gthreads = (long long)N * FEAT;
        gnn_gather<<<(int)((gthreads + 255) / 256), 256, 0, stream>>>(
            bins, cnt, weight, out, N, cap);
    } else {
        // Workspace too small: original atomic path.
        gnn_init_out<<<(total + 255) / 256, 256, 0, stream>>>(bias, out, total);
        long long threads = (long long)E * FEAT;
        int blocks = (int)((threads + 255) / 256);
        gnn_scatter<<<blocks, 256, 0, stream>>>(
            edge_row, edge_col, edge_val, weight, out, E);
    }
}